// Round 4
// baseline (625.962 us; speedup 1.0000x reference)
//
#include <hip/hip_runtime.h>
#include <math.h>

#define N_FEAT_IN 256
#define N_HID 64
#define N_OUT 16
#define EPS 0.1f

// ---------------- degree / norm ----------------

__global__ void init_deg(float* __restrict__ deg, int N) {
    int i = blockIdx.x * blockDim.x + threadIdx.x;
    if (i < N) deg[i] = 1.0f;  // self loop
}

__global__ void count_deg(const int* __restrict__ col, float* __restrict__ deg, int E) {
    int e = blockIdx.x * blockDim.x + threadIdx.x;
    if (e < E) atomicAdd(&deg[col[e]], 1.0f);
}

__global__ void finish_dinv(float* __restrict__ deg, int N) {
    int i = blockIdx.x * blockDim.x + threadIdx.x;
    if (i < N) deg[i] = rsqrtf(deg[i]);  // deg >= 1 always (self loop)
}

// ---------------- h = relu(x @ W1 + b1), one wave per row ----------------

__global__ void gemm1_relu(const float* __restrict__ x, const float* __restrict__ W1,
                           const float* __restrict__ b1, float* __restrict__ h, int N) {
    int t = blockIdx.x * blockDim.x + threadIdx.x;
    int r = t >> 6;        // row = wave
    int c = t & 63;        // lane = output column
    if (r >= N) return;
    const float4* xr = reinterpret_cast<const float4*>(x + (long long)r * N_FEAT_IN);
    float acc = b1[c];
#pragma unroll 4
    for (int k4 = 0; k4 < N_FEAT_IN / 4; ++k4) {
        float4 xv = xr[k4];
        int k = k4 * 4;
        acc = fmaf(xv.x, W1[(k + 0) * N_HID + c], acc);
        acc = fmaf(xv.y, W1[(k + 1) * N_HID + c], acc);
        acc = fmaf(xv.z, W1[(k + 2) * N_HID + c], acc);
        acc = fmaf(xv.w, W1[(k + 3) * N_HID + c], acc);
    }
    h[(long long)r * N_HID + c] = fmaxf(acc, 0.0f);
}

// ---------------- zero a float buffer ----------------

__global__ void zero_buf(float* __restrict__ p, long long n) {
    long long i = (long long)blockIdx.x * blockDim.x + threadIdx.x;
    if (i < n) p[i] = 0.0f;
}

// ---------------- edge scatter: B[col] += dinv[row]*dinv[col]*A[row] ----------------
// one wave per edge, lane = feature

__global__ void scatter_edges(const int* __restrict__ row, const int* __restrict__ col,
                              const float* __restrict__ dinv,
                              const float* __restrict__ A, float* __restrict__ B, int E) {
    int t = blockIdx.x * blockDim.x + threadIdx.x;
    int e = t >> 6;
    int lane = t & 63;
    if (e >= E) return;
    int r = row[e];
    int c = col[e];
    float w = dinv[r] * dinv[c];
    float v = w * A[(long long)r * N_HID + lane];
    atomicAdd(&B[(long long)c * N_HID + lane], v);
}

// ---------------- combine: self-loop + gate ----------------
// x_l_total = B + dinv^2 * A ; out = x_l_total * (gate*(1+eps) - eps)
// gate = sigmoid(dot(A[i], att_l)) ; one wave per node, lane = feature

__global__ void combine_gate(const float* __restrict__ A, float* __restrict__ B,
                             const float* __restrict__ dinv,
                             const float* __restrict__ att_l, int N) {
    int t = blockIdx.x * blockDim.x + threadIdx.x;
    int i = t >> 6;
    int j = t & 63;
    if (i >= N) return;
    float a = A[(long long)i * N_HID + j];
    float prod = a * att_l[j];
    // full-wave (64 lane) butterfly sum
#pragma unroll
    for (int off = 32; off > 0; off >>= 1)
        prod += __shfl_xor(prod, off, 64);
    float gate = 1.0f / (1.0f + expf(-prod));
    float factor = gate * (1.0f + EPS) - EPS;
    float d = dinv[i];
    float xl = B[(long long)i * N_HID + j] + d * d * a;
    B[(long long)i * N_HID + j] = xl * factor;
}

// ---------------- out = h @ W2 + b2, 16 lanes per row ----------------

__global__ void gemm2(const float* __restrict__ h, const float* __restrict__ W2,
                      const float* __restrict__ b2, float* __restrict__ out, int N) {
    int t = blockIdx.x * blockDim.x + threadIdx.x;
    int r = t >> 4;
    int c = t & 15;
    if (r >= N) return;
    const float4* hr = reinterpret_cast<const float4*>(h + (long long)r * N_HID);
    float acc = b2[c];
#pragma unroll
    for (int k4 = 0; k4 < N_HID / 4; ++k4) {
        float4 hv = hr[k4];
        int k = k4 * 4;
        acc = fmaf(hv.x, W2[(k + 0) * N_OUT + c], acc);
        acc = fmaf(hv.y, W2[(k + 1) * N_OUT + c], acc);
        acc = fmaf(hv.z, W2[(k + 2) * N_OUT + c], acc);
        acc = fmaf(hv.w, W2[(k + 3) * N_OUT + c], acc);
    }
    out[(long long)r * N_OUT + c] = acc;
}

extern "C" void kernel_launch(void* const* d_in, const int* in_sizes, int n_in,
                              void* d_out, int out_size, void* d_ws, size_t ws_size,
                              hipStream_t stream) {
    const float* x   = (const float*)d_in[0];   // [N, 256]
    const int*   ei  = (const int*)d_in[1];     // [2, E] flat
    const float* W1  = (const float*)d_in[2];   // [256, 64]
    const float* b1  = (const float*)d_in[3];   // [64]
    const float* att = (const float*)d_in[4];   // [L, 1, 64]
    const float* W2  = (const float*)d_in[5];   // [64, 16]
    const float* b2  = (const float*)d_in[6];   // [16]
    float* out = (float*)d_out;                 // [N, 16]

    const int N = in_sizes[0] / N_FEAT_IN;      // 50000
    const int E = in_sizes[1] / 2;              // 800000
    const int L = in_sizes[4] / N_HID;          // 2 layers

    const int* row = ei;        // edge_index[0]
    const int* col = ei + E;    // edge_index[1]

    // workspace layout: dinv [N] | bufA [N*64] | bufB [N*64]
    float* dinv = (float*)d_ws;
    long long nAlign = ((long long)N + 63) & ~63LL;
    float* bufA = dinv + nAlign;
    float* bufB = bufA + (long long)N * N_HID;

    const int TB = 256;

    // 1) degree -> dinv (recomputed every call; no persistent state)
    init_deg<<<(N + TB - 1) / TB, TB, 0, stream>>>(dinv, N);
    count_deg<<<(E + TB - 1) / TB, TB, 0, stream>>>(col, dinv, E);
    finish_dinv<<<(N + TB - 1) / TB, TB, 0, stream>>>(dinv, N);

    // 2) h = relu(x @ W1 + b1) -> bufA
    {
        long long threads = (long long)N * 64;
        gemm1_relu<<<(int)((threads + TB - 1) / TB), TB, 0, stream>>>(x, W1, b1, bufA, N);
    }

    // 3) FAGCN conv layers (ping-pong bufA <-> bufB)
    float* A = bufA;
    float* B = bufB;
    for (int l = 0; l < L; ++l) {
        long long nB = (long long)N * N_HID;
        zero_buf<<<(int)((nB + TB - 1) / TB), TB, 0, stream>>>(B, nB);
        {
            long long threads = (long long)E * 64;
            scatter_edges<<<(int)((threads + TB - 1) / TB), TB, 0, stream>>>(row, col, dinv, A, B, E);
        }
        {
            long long threads = (long long)N * 64;
            combine_gate<<<(int)((threads + TB - 1) / TB), TB, 0, stream>>>(A, B, dinv, att + (long long)l * N_HID, N);
        }
        float* tmp = A; A = B; B = tmp;
    }

    // 4) out = A @ W2 + b2
    {
        long long threads = (long long)N * N_OUT;
        gemm2<<<(int)((threads + TB - 1) / TB), TB, 0, stream>>>(A, W2, b2, out, N);
    }
}

// Round 5
// 292.975 us; speedup vs baseline: 2.1366x; 2.1366x over previous
//
#include <hip/hip_runtime.h>
#include <math.h>

#define N_FEAT_IN 256
#define N_HID 64
#define N_OUT 16
#define EPS 0.1f

__device__ inline float readlane_f(float v, int l) {
    int i = __builtin_amdgcn_readlane(__builtin_bit_cast(int, v), l);
    return __builtin_bit_cast(float, i);
}

// ---------------- small utility kernels ----------------

__global__ void zero_int(int* __restrict__ p, int n) {
    int i = blockIdx.x * blockDim.x + threadIdx.x;
    if (i < n) p[i] = 0;
}

__global__ void hist_col(const int* __restrict__ col, int* __restrict__ cnt, int E) {
    int e = blockIdx.x * blockDim.x + threadIdx.x;
    if (e < E) atomicAdd(&cnt[col[e]], 1);
}

__global__ void make_dinv(const int* __restrict__ cnt, float* __restrict__ dinv, int N) {
    int i = blockIdx.x * blockDim.x + threadIdx.x;
    if (i < N) dinv[i] = rsqrtf(1.0f + (float)cnt[i]);  // +1 for self loop
}

// ---------------- 2-level exclusive scan (N <= 256*256) ----------------

__global__ void scan_chunks(const int* __restrict__ cnt, int* __restrict__ rowptr,
                            int* __restrict__ partial, int N) {
    __shared__ int sm[256];
    int tid = threadIdx.x;
    int gid = blockIdx.x * 256 + tid;
    int v = (gid < N) ? cnt[gid] : 0;
    sm[tid] = v;
    __syncthreads();
#pragma unroll
    for (int off = 1; off < 256; off <<= 1) {
        int add = (tid >= off) ? sm[tid - off] : 0;
        __syncthreads();
        sm[tid] += add;
        __syncthreads();
    }
    if (gid < N) rowptr[gid] = sm[tid] - v;              // exclusive within chunk
    if (tid == 255) partial[blockIdx.x] = sm[255];       // chunk total
}

__global__ void scan_partials(int* __restrict__ partial, int nchunks) {
    __shared__ int sm[256];
    int tid = threadIdx.x;
    int v = (tid < nchunks) ? partial[tid] : 0;
    sm[tid] = v;
    __syncthreads();
#pragma unroll
    for (int off = 1; off < 256; off <<= 1) {
        int add = (tid >= off) ? sm[tid - off] : 0;
        __syncthreads();
        sm[tid] += add;
        __syncthreads();
    }
    if (tid < nchunks) partial[tid] = sm[tid] - v;       // exclusive chunk offsets
}

__global__ void scan_finish(int* __restrict__ rowptr, const int* __restrict__ partial,
                            int* __restrict__ pos, int N, int E) {
    int gid = blockIdx.x * 256 + threadIdx.x;
    if (gid < N) {
        int r = rowptr[gid] + partial[blockIdx.x];
        rowptr[gid] = r;
        pos[gid] = r;
    }
    if (gid == 0) rowptr[N] = E;
}

__global__ void csr_fill(const int* __restrict__ row, const int* __restrict__ col,
                         int* __restrict__ pos, int* __restrict__ srcidx, int E) {
    int e = blockIdx.x * blockDim.x + threadIdx.x;
    if (e < E) {
        int p = atomicAdd(&pos[col[e]], 1);
        srcidx[p] = row[e];
    }
}

// ---------------- h = relu(x @ W1 + b1) ----------------
// W1^T staged in LDS, XOR-swizzled for conflict-free ds_read_b128.
// One wave per 4 rows; the x rows live in wave registers (1 float4/lane/row),
// broadcast per-k via v_readlane (uniform index -> SGPR FMA operand).

__global__ __launch_bounds__(256) void gemm1_relu(const float* __restrict__ x,
                                                  const float* __restrict__ W1,
                                                  const float* __restrict__ b1,
                                                  float* __restrict__ h,
                                                  int N, int totalWaves) {
    __shared__ float w1t[64 * 256];  // 64 KB: column-major W1, swizzled
    int tid = threadIdx.x;
    // stage: element (k,c) -> byte c*1024 + ((k*4) ^ ((c&7)<<4))
    for (int idx = tid; idx < 256 * 64; idx += 256) {
        int k = idx >> 6, c = idx & 63;
        float v = W1[idx];  // W1[k][c], coalesced
        int byte = (c << 10) + ((k << 2) ^ ((c & 7) << 4));
        *reinterpret_cast<float*>(reinterpret_cast<char*>(w1t) + byte) = v;
    }
    __syncthreads();

    int lane = tid & 63;
    int w = blockIdx.x * 4 + (tid >> 6);
    float bias = b1[lane];
    int stride = totalWaves * 4;
    int g = w * 4;
    if (g >= N) return;

    const float4* xf = reinterpret_cast<const float4*>(x);
    float4 xv[4];
#pragma unroll
    for (int r = 0; r < 4; ++r) xv[r] = xf[(size_t)(g + r) * 64 + lane];

    const char* wbase = reinterpret_cast<const char*>(w1t) + (lane << 10);
    const int swz = (lane & 7) << 4;

    for (; g < N; g += stride) {
        float4 xc[4];
#pragma unroll
        for (int r = 0; r < 4; ++r) xc[r] = xv[r];
        int gn = g + stride;
        if (gn < N) {  // prefetch next group while computing this one
#pragma unroll
            for (int r = 0; r < 4; ++r) xv[r] = xf[(size_t)(gn + r) * 64 + lane];
        }
        float acc[4] = {bias, bias, bias, bias};
#pragma unroll 4
        for (int k4 = 0; k4 < 64; ++k4) {
            float4 wv = *reinterpret_cast<const float4*>(wbase + ((k4 << 4) ^ swz));
#pragma unroll
            for (int r = 0; r < 4; ++r) {
                acc[r] = fmaf(readlane_f(xc[r].x, k4), wv.x, acc[r]);
                acc[r] = fmaf(readlane_f(xc[r].y, k4), wv.y, acc[r]);
                acc[r] = fmaf(readlane_f(xc[r].z, k4), wv.z, acc[r]);
                acc[r] = fmaf(readlane_f(xc[r].w, k4), wv.w, acc[r]);
            }
        }
#pragma unroll
        for (int r = 0; r < 4; ++r)
            h[(size_t)(g + r) * 64 + lane] = fmaxf(acc[r], 0.0f);
    }
}

// ---------------- fused FAGCN layer: CSR gather + self loop + gate ----------------
// one wave per node, lane = feature; register accumulation, no atomics, no zeroing

__global__ void fagcn_gather(const float* __restrict__ A, float* __restrict__ B,
                             const float* __restrict__ dinv,
                             const int* __restrict__ rowptr, const int* __restrict__ srcidx,
                             const float* __restrict__ att_l, int N) {
    int t = blockIdx.x * blockDim.x + threadIdx.x;
    int i = t >> 6;
    int lane = t & 63;
    if (i >= N) return;
    int start = rowptr[i];
    int end = rowptr[i + 1];
    float a = A[(size_t)i * N_HID + lane];
    float acc0 = 0.0f, acc1 = 0.0f;
    int j = start;
    for (; j + 1 < end; j += 2) {
        int s0 = srcidx[j];
        int s1 = srcidx[j + 1];
        float w0 = dinv[s0];
        float w1 = dinv[s1];
        acc0 = fmaf(w0, A[(size_t)s0 * N_HID + lane], acc0);
        acc1 = fmaf(w1, A[(size_t)s1 * N_HID + lane], acc1);
    }
    if (j < end) {
        int s = srcidx[j];
        acc0 = fmaf(dinv[s], A[(size_t)s * N_HID + lane], acc0);
    }
    float d = dinv[i];
    float xl = d * (acc0 + acc1 + d * a);  // neighbors + self loop (norm d*d)
    // gate = sigmoid(dot(a_row, att_l)) via 64-lane butterfly
    float prod = a * att_l[lane];
#pragma unroll
    for (int off = 32; off > 0; off >>= 1)
        prod += __shfl_xor(prod, off, 64);
    float gate = 1.0f / (1.0f + expf(-prod));
    B[(size_t)i * N_HID + lane] = xl * (gate * (1.0f + EPS) - EPS);
}

// ---------------- out = h @ W2 + b2, 16 lanes per row ----------------

__global__ void gemm2(const float* __restrict__ h, const float* __restrict__ W2,
                      const float* __restrict__ b2, float* __restrict__ out, int N) {
    int t = blockIdx.x * blockDim.x + threadIdx.x;
    int r = t >> 4;
    int c = t & 15;
    if (r >= N) return;
    const float4* hr = reinterpret_cast<const float4*>(h + (size_t)r * N_HID);
    float acc = b2[c];
#pragma unroll
    for (int k4 = 0; k4 < N_HID / 4; ++k4) {
        float4 hv = hr[k4];
        int k = k4 * 4;
        acc = fmaf(hv.x, W2[(k + 0) * N_OUT + c], acc);
        acc = fmaf(hv.y, W2[(k + 1) * N_OUT + c], acc);
        acc = fmaf(hv.z, W2[(k + 2) * N_OUT + c], acc);
        acc = fmaf(hv.w, W2[(k + 3) * N_OUT + c], acc);
    }
    out[(size_t)r * N_OUT + c] = acc;
}

extern "C" void kernel_launch(void* const* d_in, const int* in_sizes, int n_in,
                              void* d_out, int out_size, void* d_ws, size_t ws_size,
                              hipStream_t stream) {
    const float* x   = (const float*)d_in[0];   // [N, 256]
    const int*   ei  = (const int*)d_in[1];     // [2, E] flat
    const float* W1  = (const float*)d_in[2];   // [256, 64]
    const float* b1  = (const float*)d_in[3];   // [64]
    const float* att = (const float*)d_in[4];   // [L, 1, 64]
    const float* W2  = (const float*)d_in[5];   // [64, 16]
    const float* b2  = (const float*)d_in[6];   // [16]
    float* out = (float*)d_out;                 // [N, 16]

    const int N = in_sizes[0] / N_FEAT_IN;      // 50000
    const int E = in_sizes[1] / 2;              // 800000
    const int L = in_sizes[4] / N_HID;          // 2 layers

    const int* row = ei;       // edge_index[0] (source)
    const int* col = ei + E;   // edge_index[1] (target)

    // workspace layout (256B-aligned regions)
    char* wp = (char*)d_ws;
    auto alloc = [&](size_t bytes) -> char* {
        char* p = wp;
        wp += (bytes + 255) & ~(size_t)255;
        return p;
    };
    float* dinv    = (float*)alloc((size_t)N * 4);
    int*   cnt     = (int*)alloc((size_t)N * 4);
    int*   rowptr  = (int*)alloc((size_t)(N + 1) * 4);
    int*   pos     = (int*)alloc((size_t)N * 4);
    int*   partial = (int*)alloc(256 * 4);
    int*   srcidx  = (int*)alloc((size_t)E * 4);
    float* bufA    = (float*)alloc((size_t)N * N_HID * 4);
    float* bufB    = (float*)alloc((size_t)N * N_HID * 4);

    const int TB = 256;
    const int nchunks = (N + TB - 1) / TB;      // 196 <= 256

    // 1) degree histogram -> dinv, CSR rowptr/pos
    zero_int<<<(N + TB - 1) / TB, TB, 0, stream>>>(cnt, N);
    hist_col<<<(E + TB - 1) / TB, TB, 0, stream>>>(col, cnt, E);
    make_dinv<<<(N + TB - 1) / TB, TB, 0, stream>>>(cnt, dinv, N);
    scan_chunks<<<nchunks, TB, 0, stream>>>(cnt, rowptr, partial, N);
    scan_partials<<<1, TB, 0, stream>>>(partial, nchunks);
    scan_finish<<<nchunks, TB, 0, stream>>>(rowptr, partial, pos, N, E);
    csr_fill<<<(E + TB - 1) / TB, TB, 0, stream>>>(row, col, pos, srcidx, E);

    // 2) h = relu(x @ W1 + b1) -> bufA
    {
        const int blocks = 512;                 // 2 per CU (64 KB LDS each)
        gemm1_relu<<<blocks, TB, 0, stream>>>(x, W1, b1, bufA, N, blocks * 4);
    }

    // 3) FAGCN layers (fused gather + self loop + gate), ping-pong
    float* A = bufA;
    float* B = bufB;
    for (int l = 0; l < L; ++l) {
        long long threads = (long long)N * N_HID;
        fagcn_gather<<<(int)((threads + TB - 1) / TB), TB, 0, stream>>>(
            A, B, dinv, rowptr, srcidx, att + (size_t)l * N_HID, N);
        float* tmp = A; A = B; B = tmp;
    }

    // 4) out = A @ W2 + b2
    {
        long long threads = (long long)N * N_OUT;
        gemm2<<<(int)((threads + TB - 1) / TB), TB, 0, stream>>>(A, W2, b2, out, N);
    }
}

// Round 6
// 217.943 us; speedup vs baseline: 2.8721x; 1.3443x over previous
//
#include <hip/hip_runtime.h>
#include <math.h>

#define N_FEAT_IN 256
#define N_HID 64
#define N_OUT 16
#define EPS 0.1f

typedef short bf16x8 __attribute__((ext_vector_type(8)));
typedef float f32x4 __attribute__((ext_vector_type(4)));

__device__ inline uint pack2(ushort a, ushort b) { return (uint)a | ((uint)b << 16); }

// truncation-based fp32 -> bf16 hi/lo split: x ~= hi + lo, |err| <= 2^-18 |x|
__device__ inline void split_bf16(float x, ushort& hi, ushort& lo) {
    uint b = __float_as_uint(x);
    hi = (ushort)(b >> 16);
    float xl = x - __uint_as_float(b & 0xffff0000u);
    lo = (ushort)(__float_as_uint(xl) >> 16);
}

// ---------------- small utility kernels ----------------

__global__ void zero_int(int* __restrict__ p, int n) {
    int i = blockIdx.x * blockDim.x + threadIdx.x;
    if (i < n) p[i] = 0;
}

__global__ void hist_col(const int* __restrict__ col, int* __restrict__ cnt, int E) {
    int e = blockIdx.x * blockDim.x + threadIdx.x;
    if (e < E) atomicAdd(&cnt[col[e]], 1);
}

__global__ void make_dinv(const int* __restrict__ cnt, float* __restrict__ dinv, int N) {
    int i = blockIdx.x * blockDim.x + threadIdx.x;
    if (i < N) dinv[i] = rsqrtf(1.0f + (float)cnt[i]);  // +1 for self loop
}

// ---------------- 2-level exclusive scan (N <= 256*256) ----------------

__global__ void scan_chunks(const int* __restrict__ cnt, int* __restrict__ rowptr,
                            int* __restrict__ partial, int N) {
    __shared__ int sm[256];
    int tid = threadIdx.x;
    int gid = blockIdx.x * 256 + tid;
    int v = (gid < N) ? cnt[gid] : 0;
    sm[tid] = v;
    __syncthreads();
#pragma unroll
    for (int off = 1; off < 256; off <<= 1) {
        int add = (tid >= off) ? sm[tid - off] : 0;
        __syncthreads();
        sm[tid] += add;
        __syncthreads();
    }
    if (gid < N) rowptr[gid] = sm[tid] - v;              // exclusive within chunk
    if (tid == 255) partial[blockIdx.x] = sm[255];       // chunk total
}

__global__ void scan_partials(int* __restrict__ partial, int nchunks) {
    __shared__ int sm[256];
    int tid = threadIdx.x;
    int v = (tid < nchunks) ? partial[tid] : 0;
    sm[tid] = v;
    __syncthreads();
#pragma unroll
    for (int off = 1; off < 256; off <<= 1) {
        int add = (tid >= off) ? sm[tid - off] : 0;
        __syncthreads();
        sm[tid] += add;
        __syncthreads();
    }
    if (tid < nchunks) partial[tid] = sm[tid] - v;       // exclusive chunk offsets
}

__global__ void scan_finish(int* __restrict__ rowptr, const int* __restrict__ partial,
                            int* __restrict__ pos, int N, int E) {
    int gid = blockIdx.x * 256 + threadIdx.x;
    if (gid < N) {
        int r = rowptr[gid] + partial[blockIdx.x];
        rowptr[gid] = r;
        pos[gid] = r;
    }
    if (gid == 0) rowptr[N] = E;
}

// pack (src, dinv[src]) per edge so the gather has one fewer random load
__global__ void csr_fill(const int* __restrict__ row, const int* __restrict__ col,
                         const float* __restrict__ dinv,
                         int* __restrict__ pos, int2* __restrict__ srcw, int E) {
    int e = blockIdx.x * blockDim.x + threadIdx.x;
    if (e < E) {
        int r = row[e];
        int p = atomicAdd(&pos[col[e]], 1);
        srcw[p] = make_int2(r, __float_as_int(dinv[r]));
    }
}

// ---------------- h = relu(x @ W1 + b1) via bf16x3 MFMA ----------------
// Each wave: 16 rows x 64 cols. W1 hi/lo fragments staged once per block in LDS.
// A/B K-mapping k=(lane>>4)*8+i is used identically for both operands
// (K-permutation invariant). C/D: col=lane&15, row=(lane>>4)*4+reg (m89-verified).

__global__ __launch_bounds__(256) void gemm1_mfma(const float* __restrict__ x,
                                                  const float* __restrict__ W1,
                                                  const float* __restrict__ b1,
                                                  float* __restrict__ h,
                                                  int MB, int totalWaves) {
    __shared__ uint4 wh_lds[2048];  // 32 KB: [ks][nt][lane] hi fragments
    __shared__ uint4 wl_lds[2048];  // 32 KB: lo fragments
    int tid = threadIdx.x;
    for (int e = tid; e < 2048; e += 256) {
        int ks = e >> 8;
        int rem = e & 255;
        int nt = rem >> 6;
        int ln = rem & 63;
        int k0 = ks * 32 + ((ln >> 4) << 3);
        int colw = nt * 16 + (ln & 15);
        ushort hi[8], lo[8];
#pragma unroll
        for (int i = 0; i < 8; ++i) {
            float v = W1[(k0 + i) * 64 + colw];
            split_bf16(v, hi[i], lo[i]);
        }
        wh_lds[e] = make_uint4(pack2(hi[0], hi[1]), pack2(hi[2], hi[3]),
                               pack2(hi[4], hi[5]), pack2(hi[6], hi[7]));
        wl_lds[e] = make_uint4(pack2(lo[0], lo[1]), pack2(lo[2], lo[3]),
                               pack2(lo[4], lo[5]), pack2(lo[6], lo[7]));
    }
    __syncthreads();

    int lane = tid & 63;
    int m = lane & 15;       // row within 16-row tile (A), col within 16-col tile (B/D)
    int kg = lane >> 4;      // k-group
    int wid = blockIdx.x * 4 + (tid >> 6);
    const bf16x8* whf = reinterpret_cast<const bf16x8*>(wh_lds);
    const bf16x8* wlf = reinterpret_cast<const bf16x8*>(wl_lds);
    float bias[4];
#pragma unroll
    for (int nt = 0; nt < 4; ++nt) bias[nt] = b1[nt * 16 + m];

    for (int mb = wid; mb < MB; mb += totalWaves) {
        const float4* xrow =
            reinterpret_cast<const float4*>(x + (size_t)(mb * 16 + m) * 256 + kg * 8);
        f32x4 acc[4] = {{0.f,0.f,0.f,0.f},{0.f,0.f,0.f,0.f},
                        {0.f,0.f,0.f,0.f},{0.f,0.f,0.f,0.f}};
#pragma unroll
        for (int ks = 0; ks < 8; ++ks) {
            float4 a0 = xrow[ks * 8];
            float4 a1 = xrow[ks * 8 + 1];
            float f[8] = {a0.x, a0.y, a0.z, a0.w, a1.x, a1.y, a1.z, a1.w};
            bf16x8 ah, al;
#pragma unroll
            for (int i = 0; i < 8; ++i) {
                ushort hu, lu;
                split_bf16(f[i], hu, lu);
                ah[i] = (short)hu;
                al[i] = (short)lu;
            }
#pragma unroll
            for (int nt = 0; nt < 4; ++nt) {
                bf16x8 wh = whf[(ks * 4 + nt) * 64 + lane];
                bf16x8 wl = wlf[(ks * 4 + nt) * 64 + lane];
                acc[nt] = __builtin_amdgcn_mfma_f32_16x16x32_bf16(ah, wh, acc[nt], 0, 0, 0);
                acc[nt] = __builtin_amdgcn_mfma_f32_16x16x32_bf16(al, wh, acc[nt], 0, 0, 0);
                acc[nt] = __builtin_amdgcn_mfma_f32_16x16x32_bf16(ah, wl, acc[nt], 0, 0, 0);
            }
        }
        int r0 = kg * 4;
        size_t base = ((size_t)(mb * 16) + r0) * 64;
#pragma unroll
        for (int nt = 0; nt < 4; ++nt) {
#pragma unroll
            for (int j = 0; j < 4; ++j) {
                h[base + (size_t)j * 64 + nt * 16 + m] = fmaxf(acc[nt][j] + bias[nt], 0.0f);
            }
        }
    }
}

// ---------------- fused FAGCN layer: CSR gather + self loop + gate ----------------
// one wave per node, lane = feature; 4 independent accumulator chains

__global__ void fagcn_gather(const float* __restrict__ A, float* __restrict__ B,
                             const float* __restrict__ dinv,
                             const int* __restrict__ rowptr, const int2* __restrict__ srcw,
                             const float* __restrict__ att_l, int N) {
    int t = blockIdx.x * blockDim.x + threadIdx.x;
    int i = t >> 6;
    int lane = t & 63;
    if (i >= N) return;
    int start = rowptr[i];
    int end = rowptr[i + 1];
    const float* Al = A + lane;
    float a = Al[(size_t)i << 6];
    float acc0 = 0.0f, acc1 = 0.0f, acc2 = 0.0f, acc3 = 0.0f;
    int j = start;
    for (; j + 3 < end; j += 4) {
        int2 e0 = srcw[j];
        int2 e1 = srcw[j + 1];
        int2 e2 = srcw[j + 2];
        int2 e3 = srcw[j + 3];
        acc0 = fmaf(__int_as_float(e0.y), Al[(size_t)e0.x << 6], acc0);
        acc1 = fmaf(__int_as_float(e1.y), Al[(size_t)e1.x << 6], acc1);
        acc2 = fmaf(__int_as_float(e2.y), Al[(size_t)e2.x << 6], acc2);
        acc3 = fmaf(__int_as_float(e3.y), Al[(size_t)e3.x << 6], acc3);
    }
    for (; j < end; ++j) {
        int2 e = srcw[j];
        acc0 = fmaf(__int_as_float(e.y), Al[(size_t)e.x << 6], acc0);
    }
    float d = dinv[i];
    float xl = d * ((acc0 + acc1) + (acc2 + acc3) + d * a);  // neighbors + self loop
    // gate = sigmoid(dot(a_row, att_l)) via 64-lane butterfly
    float prod = a * att_l[lane];
#pragma unroll
    for (int off = 32; off > 0; off >>= 1)
        prod += __shfl_xor(prod, off, 64);
    float gate = 1.0f / (1.0f + expf(-prod));
    B[(size_t)i * N_HID + lane] = xl * (gate * (1.0f + EPS) - EPS);
}

// ---------------- out = h @ W2 + b2, 16 lanes per row ----------------

__global__ void gemm2(const float* __restrict__ h, const float* __restrict__ W2,
                      const float* __restrict__ b2, float* __restrict__ out, int N) {
    int t = blockIdx.x * blockDim.x + threadIdx.x;
    int r = t >> 4;
    int c = t & 15;
    if (r >= N) return;
    const float4* hr = reinterpret_cast<const float4*>(h + (size_t)r * N_HID);
    float acc = b2[c];
#pragma unroll
    for (int k4 = 0; k4 < N_HID / 4; ++k4) {
        float4 hv = hr[k4];
        int k = k4 * 4;
        acc = fmaf(hv.x, W2[(k + 0) * N_OUT + c], acc);
        acc = fmaf(hv.y, W2[(k + 1) * N_OUT + c], acc);
        acc = fmaf(hv.z, W2[(k + 2) * N_OUT + c], acc);
        acc = fmaf(hv.w, W2[(k + 3) * N_OUT + c], acc);
    }
    out[(size_t)r * N_OUT + c] = acc;
}

extern "C" void kernel_launch(void* const* d_in, const int* in_sizes, int n_in,
                              void* d_out, int out_size, void* d_ws, size_t ws_size,
                              hipStream_t stream) {
    const float* x   = (const float*)d_in[0];   // [N, 256]
    const int*   ei  = (const int*)d_in[1];     // [2, E] flat
    const float* W1  = (const float*)d_in[2];   // [256, 64]
    const float* b1  = (const float*)d_in[3];   // [64]
    const float* att = (const float*)d_in[4];   // [L, 1, 64]
    const float* W2  = (const float*)d_in[5];   // [64, 16]
    const float* b2  = (const float*)d_in[6];   // [16]
    float* out = (float*)d_out;                 // [N, 16]

    const int N = in_sizes[0] / N_FEAT_IN;      // 50000
    const int E = in_sizes[1] / 2;              // 800000
    const int L = in_sizes[4] / N_HID;          // 2 layers

    const int* row = ei;       // edge_index[0] (source)
    const int* col = ei + E;   // edge_index[1] (target)

    // workspace layout (256B-aligned regions)
    char* wp = (char*)d_ws;
    auto alloc = [&](size_t bytes) -> char* {
        char* p = wp;
        wp += (bytes + 255) & ~(size_t)255;
        return p;
    };
    float* dinv    = (float*)alloc((size_t)N * 4);
    int*   cnt     = (int*)alloc((size_t)N * 4);
    int*   rowptr  = (int*)alloc((size_t)(N + 1) * 4);
    int*   pos     = (int*)alloc((size_t)N * 4);
    int*   partial = (int*)alloc(256 * 4);
    int2*  srcw    = (int2*)alloc((size_t)E * 8);
    float* bufA    = (float*)alloc((size_t)N * N_HID * 4);
    float* bufB    = (float*)alloc((size_t)N * N_HID * 4);

    const int TB = 256;
    const int nchunks = (N + TB - 1) / TB;      // 196 <= 256

    // 1) degree histogram -> dinv, CSR rowptr/pos, packed (src,w) edge list
    zero_int<<<(N + TB - 1) / TB, TB, 0, stream>>>(cnt, N);
    hist_col<<<(E + TB - 1) / TB, TB, 0, stream>>>(col, cnt, E);
    make_dinv<<<(N + TB - 1) / TB, TB, 0, stream>>>(cnt, dinv, N);
    scan_chunks<<<nchunks, TB, 0, stream>>>(cnt, rowptr, partial, N);
    scan_partials<<<1, TB, 0, stream>>>(partial, nchunks);
    scan_finish<<<nchunks, TB, 0, stream>>>(rowptr, partial, pos, N, E);
    csr_fill<<<(E + TB - 1) / TB, TB, 0, stream>>>(row, col, dinv, pos, srcw, E);

    // 2) h = relu(x @ W1 + b1) -> bufA  (bf16x3 MFMA)
    {
        const int blocks = 512;                 // 64 KB LDS -> 2 blocks/CU
        const int MB = N / 16;                  // 3125 row-blocks
        gemm1_mfma<<<blocks, TB, 0, stream>>>(x, W1, b1, bufA, MB, blocks * 4);
    }

    // 3) FAGCN layers (fused gather + self loop + gate), ping-pong
    float* A = bufA;
    float* B = bufB;
    for (int l = 0; l < L; ++l) {
        long long threads = (long long)N * N_HID;
        fagcn_gather<<<(int)((threads + TB - 1) / TB), TB, 0, stream>>>(
            A, B, dinv, rowptr, srcw, att + (size_t)l * N_HID, N);
        float* tmp = A; A = B; B = tmp;
    }

    // 4) out = A @ W2 + b2
    {
        long long threads = (long long)N * N_OUT;
        gemm2<<<(int)((threads + TB - 1) / TB), TB, 0, stream>>>(A, W2, b2, out, N);
    }
}

// Round 7
// 207.135 us; speedup vs baseline: 3.0220x; 1.0522x over previous
//
#include <hip/hip_runtime.h>
#include <math.h>

#define N_FEAT_IN 256
#define N_HID 64
#define N_OUT 16
#define EPS 0.1f

typedef short bf16x8 __attribute__((ext_vector_type(8)));
typedef float f32x4 __attribute__((ext_vector_type(4)));

__device__ inline uint pack2(ushort a, ushort b) { return (uint)a | ((uint)b << 16); }

// fp32 -> bf16 round-to-nearest-even (inputs finite; no NaN handling needed)
__device__ inline ushort bf16_rne(float x) {
    uint b = __float_as_uint(x);
    b += 0x7fff + ((b >> 16) & 1);
    return (ushort)(b >> 16);
}

// truncation-based fp32 -> bf16 hi/lo split: x ~= hi + lo, |err| <= 2^-18 |x|
__device__ inline void split_bf16(float x, ushort& hi, ushort& lo) {
    uint b = __float_as_uint(x);
    hi = (ushort)(b >> 16);
    float xl = x - __uint_as_float(b & 0xffff0000u);
    lo = (ushort)(__float_as_uint(xl) >> 16);
}

// ---------------- degree histogram ----------------

__global__ void hist_col(const int* __restrict__ col, int* __restrict__ cnt, int E) {
    int e = blockIdx.x * blockDim.x + threadIdx.x;
    if (e < E) atomicAdd(&cnt[col[e]], 1);
}

// ---------------- 2-level exclusive scan (N <= 256*256), dinv fused ----------------

__global__ void scan_chunks(const int* __restrict__ cnt, int* __restrict__ rowptr,
                            int* __restrict__ partial, float* __restrict__ dinv, int N) {
    __shared__ int sm[256];
    int tid = threadIdx.x;
    int gid = blockIdx.x * 256 + tid;
    int v = (gid < N) ? cnt[gid] : 0;
    sm[tid] = v;
    __syncthreads();
#pragma unroll
    for (int off = 1; off < 256; off <<= 1) {
        int add = (tid >= off) ? sm[tid - off] : 0;
        __syncthreads();
        sm[tid] += add;
        __syncthreads();
    }
    if (gid < N) {
        rowptr[gid] = sm[tid] - v;               // exclusive within chunk
        dinv[gid] = rsqrtf(1.0f + (float)v);     // +1 for self loop
    }
    if (tid == 255) partial[blockIdx.x] = sm[255];
}

__global__ void scan_partials(int* __restrict__ partial, int nchunks) {
    __shared__ int sm[256];
    int tid = threadIdx.x;
    int v = (tid < nchunks) ? partial[tid] : 0;
    sm[tid] = v;
    __syncthreads();
#pragma unroll
    for (int off = 1; off < 256; off <<= 1) {
        int add = (tid >= off) ? sm[tid - off] : 0;
        __syncthreads();
        sm[tid] += add;
        __syncthreads();
    }
    if (tid < nchunks) partial[tid] = sm[tid] - v;
}

__global__ void scan_finish(int* __restrict__ rowptr, const int* __restrict__ partial,
                            int* __restrict__ pos, int N, int E) {
    int gid = blockIdx.x * 256 + threadIdx.x;
    if (gid < N) {
        int r = rowptr[gid] + partial[blockIdx.x];
        rowptr[gid] = r;
        pos[gid] = r;
    }
    if (gid == 0) rowptr[N] = E;
}

// 2-byte payload: per-edge weight eliminated by pre-scaling node features by dinv
__global__ void csr_fill(const int* __restrict__ row, const int* __restrict__ col,
                         int* __restrict__ pos, ushort* __restrict__ srcidx, int E) {
    int e = blockIdx.x * blockDim.x + threadIdx.x;
    if (e < E) {
        int p = atomicAdd(&pos[col[e]], 1);
        srcidx[p] = (ushort)row[e];
    }
}

// ---------------- As1 = dinv * relu(x @ W1 + b1), bf16-packed, via bf16x3 MFMA --------
// Each wave: 16 rows x 64 cols. W1 hi/lo fragments staged once per block in LDS.
// A/B K-mapping k=(lane>>4)*8+i used identically for both operands (K-perm invariant).
// C/D: col=lane&15, row=(lane>>4)*4+reg.

__global__ __launch_bounds__(256) void gemm1_mfma(const float* __restrict__ x,
                                                  const float* __restrict__ W1,
                                                  const float* __restrict__ b1,
                                                  const float* __restrict__ dinv,
                                                  uint* __restrict__ AsOut,
                                                  int MB, int totalWaves) {
    __shared__ uint4 wh_lds[2048];  // 32 KB: [ks][nt][lane] hi fragments
    __shared__ uint4 wl_lds[2048];  // 32 KB: lo fragments
    int tid = threadIdx.x;
    for (int e = tid; e < 2048; e += 256) {
        int ks = e >> 8;
        int rem = e & 255;
        int nt = rem >> 6;
        int ln = rem & 63;
        int k0 = ks * 32 + ((ln >> 4) << 3);
        int colw = nt * 16 + (ln & 15);
        ushort hi[8], lo[8];
#pragma unroll
        for (int i = 0; i < 8; ++i) {
            float v = W1[(k0 + i) * 64 + colw];
            split_bf16(v, hi[i], lo[i]);
        }
        wh_lds[e] = make_uint4(pack2(hi[0], hi[1]), pack2(hi[2], hi[3]),
                               pack2(hi[4], hi[5]), pack2(hi[6], hi[7]));
        wl_lds[e] = make_uint4(pack2(lo[0], lo[1]), pack2(lo[2], lo[3]),
                               pack2(lo[4], lo[5]), pack2(lo[6], lo[7]));
    }
    __syncthreads();

    int lane = tid & 63;
    int m = lane & 15;
    int kg = lane >> 4;
    int wid = blockIdx.x * 4 + (tid >> 6);
    const bf16x8* whf = reinterpret_cast<const bf16x8*>(wh_lds);
    const bf16x8* wlf = reinterpret_cast<const bf16x8*>(wl_lds);
    float bias[4];
#pragma unroll
    for (int nt = 0; nt < 4; ++nt) bias[nt] = b1[nt * 16 + m];

    for (int mb = wid; mb < MB; mb += totalWaves) {
        const float4* xrow =
            reinterpret_cast<const float4*>(x + (size_t)(mb * 16 + m) * 256 + kg * 8);
        f32x4 acc[4] = {{0.f,0.f,0.f,0.f},{0.f,0.f,0.f,0.f},
                        {0.f,0.f,0.f,0.f},{0.f,0.f,0.f,0.f}};
#pragma unroll
        for (int ks = 0; ks < 8; ++ks) {
            float4 a0 = xrow[ks * 8];
            float4 a1 = xrow[ks * 8 + 1];
            float f[8] = {a0.x, a0.y, a0.z, a0.w, a1.x, a1.y, a1.z, a1.w};
            bf16x8 ah, al;
#pragma unroll
            for (int i = 0; i < 8; ++i) {
                ushort hu, lu;
                split_bf16(f[i], hu, lu);
                ah[i] = (short)hu;
                al[i] = (short)lu;
            }
#pragma unroll
            for (int nt = 0; nt < 4; ++nt) {
                bf16x8 wh = whf[(ks * 4 + nt) * 64 + lane];
                bf16x8 wl = wlf[(ks * 4 + nt) * 64 + lane];
                acc[nt] = __builtin_amdgcn_mfma_f32_16x16x32_bf16(ah, wh, acc[nt], 0, 0, 0);
                acc[nt] = __builtin_amdgcn_mfma_f32_16x16x32_bf16(al, wh, acc[nt], 0, 0, 0);
                acc[nt] = __builtin_amdgcn_mfma_f32_16x16x32_bf16(ah, wl, acc[nt], 0, 0, 0);
            }
        }
        int r0 = mb * 16 + kg * 4;
        float dr[4];
#pragma unroll
        for (int j = 0; j < 4; ++j) dr[j] = dinv[r0 + j];
#pragma unroll
        for (int nt = 0; nt < 4; ++nt) {
#pragma unroll
            for (int j = 0; j < 4; ++j) {
                float v = fmaxf(acc[nt][j] + bias[nt], 0.0f) * dr[j];
                float p = __shfl_xor(v, 1, 64);  // partner column (m^1)
                if ((m & 1) == 0) {
                    uint u = pack2(bf16_rne(v), bf16_rne(p));
                    AsOut[(size_t)(r0 + j) * 32 + ((nt * 16 + m) >> 1)] = u;
                }
            }
        }
    }
}

// ---------------- fused FAGCN layer over pre-scaled bf16 features ----------------
// one wave per node; lanes 0-31 own feature pairs (2q,2q+1), lanes 32-63 mirror.
// acc = sum_{r in nbr} As[r]; x_l = d*(acc + As[i]); gate from As[i]/d;
// write next layer's pre-scaled input (bf16) or final h (f32).

template <bool LAST>
__global__ void fagcn_layer(const uint* __restrict__ As, void* __restrict__ Out,
                            const float* __restrict__ dinv,
                            const int* __restrict__ rowptr,
                            const ushort* __restrict__ src,
                            const float* __restrict__ att_l, int N) {
    int t = blockIdx.x * blockDim.x + threadIdx.x;
    int i = t >> 6;
    int lane = t & 63;
    int q = lane & 31;
    if (i >= N) return;
    int start = rowptr[i];
    int end = rowptr[i + 1];
    uint su = As[(size_t)i * 32 + q];
    float self0 = __uint_as_float(su << 16);
    float self1 = __uint_as_float(su & 0xffff0000u);
    float a0 = 0.f, a1 = 0.f, b0 = 0.f, b1 = 0.f;
    int j = start;
    for (; j + 3 < end; j += 4) {
        int s0 = src[j];
        int s1 = src[j + 1];
        int s2 = src[j + 2];
        int s3 = src[j + 3];
        uint u0 = As[(size_t)s0 * 32 + q];
        uint u1 = As[(size_t)s1 * 32 + q];
        uint u2 = As[(size_t)s2 * 32 + q];
        uint u3 = As[(size_t)s3 * 32 + q];
        a0 += __uint_as_float(u0 << 16); a1 += __uint_as_float(u0 & 0xffff0000u);
        b0 += __uint_as_float(u1 << 16); b1 += __uint_as_float(u1 & 0xffff0000u);
        a0 += __uint_as_float(u2 << 16); a1 += __uint_as_float(u2 & 0xffff0000u);
        b0 += __uint_as_float(u3 << 16); b1 += __uint_as_float(u3 & 0xffff0000u);
    }
    for (; j < end; ++j) {
        int s = src[j];
        uint u = As[(size_t)s * 32 + q];
        a0 += __uint_as_float(u << 16);
        a1 += __uint_as_float(u & 0xffff0000u);
    }
    float acc0 = a0 + b0;
    float acc1 = a1 + b1;
    float d = dinv[i];
    // gate = sigmoid(dot(h_row, att)) with h = As/d
    float2 at = reinterpret_cast<const float2*>(att_l)[q];
    float prod = self0 * at.x + self1 * at.y;
#pragma unroll
    for (int off = 16; off > 0; off >>= 1)
        prod += __shfl_xor(prod, off, 64);   // fold within each 32-lane half
    float gate = 1.0f / (1.0f + expf(-prod / d));
    float factor = gate * (1.0f + EPS) - EPS;
    float h0 = d * (acc0 + self0) * factor;
    float h1 = d * (acc1 + self1) * factor;
    if (lane < 32) {
        if (LAST) {
            reinterpret_cast<float2*>(Out)[(size_t)i * 32 + q] = make_float2(h0, h1);
        } else {
            reinterpret_cast<uint*>(Out)[(size_t)i * 32 + q] =
                pack2(bf16_rne(d * h0), bf16_rne(d * h1));
        }
    }
}

// ---------------- out = h @ W2 + b2, 16 lanes per row ----------------

__global__ void gemm2(const float* __restrict__ h, const float* __restrict__ W2,
                      const float* __restrict__ b2, float* __restrict__ out, int N) {
    int t = blockIdx.x * blockDim.x + threadIdx.x;
    int r = t >> 4;
    int c = t & 15;
    if (r >= N) return;
    const float4* hr = reinterpret_cast<const float4*>(h + (size_t)r * N_HID);
    float acc = b2[c];
#pragma unroll
    for (int k4 = 0; k4 < N_HID / 4; ++k4) {
        float4 hv = hr[k4];
        int k = k4 * 4;
        acc = fmaf(hv.x, W2[(k + 0) * N_OUT + c], acc);
        acc = fmaf(hv.y, W2[(k + 1) * N_OUT + c], acc);
        acc = fmaf(hv.z, W2[(k + 2) * N_OUT + c], acc);
        acc = fmaf(hv.w, W2[(k + 3) * N_OUT + c], acc);
    }
    out[(size_t)r * N_OUT + c] = acc;
}

extern "C" void kernel_launch(void* const* d_in, const int* in_sizes, int n_in,
                              void* d_out, int out_size, void* d_ws, size_t ws_size,
                              hipStream_t stream) {
    const float* x   = (const float*)d_in[0];   // [N, 256]
    const int*   ei  = (const int*)d_in[1];     // [2, E] flat (int32 per harness)
    const float* W1  = (const float*)d_in[2];   // [256, 64]
    const float* b1  = (const float*)d_in[3];   // [64]
    const float* att = (const float*)d_in[4];   // [L, 1, 64]
    const float* W2  = (const float*)d_in[5];   // [64, 16]
    const float* b2  = (const float*)d_in[6];   // [16]
    float* out = (float*)d_out;                 // [N, 16]

    const int N = in_sizes[0] / N_FEAT_IN;      // 50000 (< 65536: ushort src ids)
    const int E = in_sizes[1] / 2;              // 800000
    const int L = in_sizes[4] / N_HID;          // 2 layers

    const int* row = ei;       // edge_index[0] (source)
    const int* col = ei + E;   // edge_index[1] (target)

    // workspace layout (256B-aligned regions)
    char* wp = (char*)d_ws;
    auto alloc = [&](size_t bytes) -> char* {
        char* p = wp;
        wp += (bytes + 255) & ~(size_t)255;
        return p;
    };
    float*  dinv    = (float*)alloc((size_t)N * 4);
    int*    cnt     = (int*)alloc((size_t)N * 4);
    int*    rowptr  = (int*)alloc((size_t)(N + 1) * 4);
    int*    pos     = (int*)alloc((size_t)N * 4);
    int*    partial = (int*)alloc(256 * 4);
    ushort* srcidx  = (ushort*)alloc((size_t)E * 2);
    uint*   AsA     = (uint*)alloc((size_t)N * 32 * 4);   // bf16-pair features
    uint*   AsB     = (uint*)alloc((size_t)N * 32 * 4);
    float*  hF      = (float*)alloc((size_t)N * N_HID * 4);  // final layer f32

    const int TB = 256;
    const int nchunks = (N + TB - 1) / TB;      // 196 <= 256

    // 1) degree histogram -> dinv + CSR rowptr/pos + ushort edge sources
    hipMemsetAsync(cnt, 0, (size_t)N * 4, stream);
    hist_col<<<(E + TB - 1) / TB, TB, 0, stream>>>(col, cnt, E);
    scan_chunks<<<nchunks, TB, 0, stream>>>(cnt, rowptr, partial, dinv, N);
    scan_partials<<<1, TB, 0, stream>>>(partial, nchunks);
    scan_finish<<<nchunks, TB, 0, stream>>>(rowptr, partial, pos, N, E);
    csr_fill<<<(E + TB - 1) / TB, TB, 0, stream>>>(row, col, pos, srcidx, E);

    // 2) As1 = dinv * relu(x @ W1 + b1) -> AsA (bf16 pairs)
    {
        const int blocks = 512;                 // 64 KB LDS -> 2 blocks/CU
        const int MB = N / 16;                  // 3125 row-tiles
        gemm1_mfma<<<blocks, TB, 0, stream>>>(x, W1, b1, dinv, AsA, MB, blocks * 4);
    }

    // 3) FAGCN layers (weight-free gather over pre-scaled features)
    {
        long long threads = (long long)N * 64;
        int grid = (int)((threads + TB - 1) / TB);
        uint* A = AsA;
        uint* B = AsB;
        for (int l = 0; l < L; ++l) {
            const float* att_l = att + (size_t)l * N_HID;
            if (l == L - 1) {
                fagcn_layer<true><<<grid, TB, 0, stream>>>(A, hF, dinv, rowptr, srcidx, att_l, N);
            } else {
                fagcn_layer<false><<<grid, TB, 0, stream>>>(A, B, dinv, rowptr, srcidx, att_l, N);
                uint* tmp = A; A = B; B = tmp;
            }
        }
    }

    // 4) out = hF @ W2 + b2
    {
        long long threads = (long long)N * N_OUT;
        gemm2<<<(int)((threads + TB - 1) / TB), TB, 0, stream>>>(hF, W2, b2, out, N);
    }
}

// Round 8
// 200.986 us; speedup vs baseline: 3.1145x; 1.0306x over previous
//
#include <hip/hip_runtime.h>
#include <math.h>

#define N_FEAT_IN 256
#define N_HID 64
#define N_OUT 16
#define EPS 0.1f

typedef short bf16x8 __attribute__((ext_vector_type(8)));
typedef float f32x4 __attribute__((ext_vector_type(4)));

__device__ inline uint pack2(ushort a, ushort b) { return (uint)a | ((uint)b << 16); }

// fp32 -> bf16 round-to-nearest-even (inputs finite; no NaN handling needed)
__device__ inline ushort bf16_rne(float x) {
    uint b = __float_as_uint(x);
    b += 0x7fff + ((b >> 16) & 1);
    return (ushort)(b >> 16);
}

// truncation-based fp32 -> bf16 hi/lo split: x ~= hi + lo, |err| <= 2^-18 |x|
__device__ inline void split_bf16(float x, ushort& hi, ushort& lo) {
    uint b = __float_as_uint(x);
    hi = (ushort)(b >> 16);
    float xl = x - __uint_as_float(b & 0xffff0000u);
    lo = (ushort)(__float_as_uint(xl) >> 16);
}

// ---------------- zero (runtime fillBuffer is 42us inside a graph; this is ~2us) ------

__global__ void zero_int(int* __restrict__ p, int n) {
    int i = blockIdx.x * blockDim.x + threadIdx.x;
    if (i < n) p[i] = 0;
}

// ---------------- XCD-range-partitioned degree histogram ----------------
// block bid handles only cols in range (bid&7); round-robin bid->XCD keeps each
// cnt line in ONE XCD's L2 (no cross-XCD line migration on the atomics).

__global__ void hist_part(const int* __restrict__ col, int* __restrict__ cnt,
                          int E, int rangeSz) {
    int r = blockIdx.x & 7;
    int nsl = gridDim.x >> 3;
    int s = blockIdx.x >> 3;
    int lo = r * rangeSz;
    int hi = lo + rangeSz;
    int stride = nsl * blockDim.x;
    for (int e = s * blockDim.x + threadIdx.x; e < E; e += stride) {
        int c = col[e];
        if (c >= lo && c < hi) atomicAdd(&cnt[c], 1);
    }
}

// ---------------- 2-level exclusive scan (N <= 256*256), dinv fused ----------------

__global__ void scan_chunks(const int* __restrict__ cnt, int* __restrict__ rowptr,
                            int* __restrict__ partial, float* __restrict__ dinv, int N) {
    __shared__ int sm[256];
    int tid = threadIdx.x;
    int gid = blockIdx.x * 256 + tid;
    int v = (gid < N) ? cnt[gid] : 0;
    sm[tid] = v;
    __syncthreads();
#pragma unroll
    for (int off = 1; off < 256; off <<= 1) {
        int add = (tid >= off) ? sm[tid - off] : 0;
        __syncthreads();
        sm[tid] += add;
        __syncthreads();
    }
    if (gid < N) {
        rowptr[gid] = sm[tid] - v;               // exclusive within chunk
        dinv[gid] = rsqrtf(1.0f + (float)v);     // +1 for self loop
    }
    if (tid == 255) partial[blockIdx.x] = sm[255];
}

__global__ void scan_partials(int* __restrict__ partial, int nchunks) {
    __shared__ int sm[256];
    int tid = threadIdx.x;
    int v = (tid < nchunks) ? partial[tid] : 0;
    sm[tid] = v;
    __syncthreads();
#pragma unroll
    for (int off = 1; off < 256; off <<= 1) {
        int add = (tid >= off) ? sm[tid - off] : 0;
        __syncthreads();
        sm[tid] += add;
        __syncthreads();
    }
    if (tid < nchunks) partial[tid] = sm[tid] - v;
}

__global__ void scan_finish(int* __restrict__ rowptr, const int* __restrict__ partial,
                            int* __restrict__ pos, int N, int E) {
    int gid = blockIdx.x * 256 + threadIdx.x;
    if (gid < N) {
        int r = rowptr[gid] + partial[blockIdx.x];
        rowptr[gid] = r;
        pos[gid] = r;
    }
    if (gid == 0) rowptr[N] = E;
}

// ---------------- XCD-range-partitioned CSR fill (2-byte payload) ----------------
// per-edge weight was eliminated by pre-scaling node features with dinv, so the
// payload is a bare ushort source id. Range partitioning keeps pos atomics and
// srcidx scatter lines XCD-local.

__global__ void csr_fill_part(const int* __restrict__ row, const int* __restrict__ col,
                              int* __restrict__ pos, ushort* __restrict__ srcidx,
                              int E, int rangeSz) {
    int r = blockIdx.x & 7;
    int nsl = gridDim.x >> 3;
    int s = blockIdx.x >> 3;
    int lo = r * rangeSz;
    int hi = lo + rangeSz;
    int stride = nsl * blockDim.x;
    for (int e = s * blockDim.x + threadIdx.x; e < E; e += stride) {
        int c = col[e];
        if (c >= lo && c < hi) {
            int p = atomicAdd(&pos[c], 1);
            srcidx[p] = (ushort)row[e];
        }
    }
}

// ---------------- As1 = dinv * relu(x @ W1 + b1), bf16-packed, via bf16x3 MFMA --------
// Each wave: 16 rows x 64 cols, register double-buffered x tiles (prefetch next
// tile's 16 float4 BEFORE the 96-MFMA compute phase so L3 latency hides).
// W1 hi/lo fragments staged once per block in LDS (64 KB -> 2 blocks/CU).
// A/B K-mapping k=(lane>>4)*8+i used identically for both operands (K-perm invariant).
// C/D: col=lane&15, row=(lane>>4)*4+reg.

__global__ __launch_bounds__(256) void gemm1_mfma(const float* __restrict__ x,
                                                  const float* __restrict__ W1,
                                                  const float* __restrict__ b1,
                                                  const float* __restrict__ dinv,
                                                  uint* __restrict__ AsOut,
                                                  int MB, int totalWaves) {
    __shared__ uint4 wh_lds[2048];  // 32 KB: [ks][nt][lane] hi fragments
    __shared__ uint4 wl_lds[2048];  // 32 KB: lo fragments
    int tid = threadIdx.x;
    for (int e = tid; e < 2048; e += 256) {
        int ks = e >> 8;
        int rem = e & 255;
        int nt = rem >> 6;
        int ln = rem & 63;
        int k0 = ks * 32 + ((ln >> 4) << 3);
        int colw = nt * 16 + (ln & 15);
        ushort hi[8], lo[8];
#pragma unroll
        for (int i = 0; i < 8; ++i) {
            float v = W1[(k0 + i) * 64 + colw];
            split_bf16(v, hi[i], lo[i]);
        }
        wh_lds[e] = make_uint4(pack2(hi[0], hi[1]), pack2(hi[2], hi[3]),
                               pack2(hi[4], hi[5]), pack2(hi[6], hi[7]));
        wl_lds[e] = make_uint4(pack2(lo[0], lo[1]), pack2(lo[2], lo[3]),
                               pack2(lo[4], lo[5]), pack2(lo[6], lo[7]));
    }
    __syncthreads();

    int lane = tid & 63;
    int m = lane & 15;
    int kg = lane >> 4;
    int wid = blockIdx.x * 4 + (tid >> 6);
    const bf16x8* whf = reinterpret_cast<const bf16x8*>(wh_lds);
    const bf16x8* wlf = reinterpret_cast<const bf16x8*>(wl_lds);
    float bias[4];
#pragma unroll
    for (int nt = 0; nt < 4; ++nt) bias[nt] = b1[nt * 16 + m];

    auto load_tile = [&](float4* dst, int mbv) {
        const float4* xr = reinterpret_cast<const float4*>(x) +
                           (size_t)(mbv * 16 + m) * 64 + kg * 2;
#pragma unroll
        for (int ks = 0; ks < 8; ++ks) {
            dst[2 * ks]     = xr[ks * 8];
            dst[2 * ks + 1] = xr[ks * 8 + 1];
        }
    };

    int mb = wid;
    if (mb >= MB) return;
    float4 xv[16], xn[16];
    load_tile(xv, mb);

    while (true) {
        int mbn = mb + totalWaves;
        bool has_next = (mbn < MB);
        if (has_next) load_tile(xn, mbn);   // issue loads early; hide under MFMA

        f32x4 acc[4] = {{0.f,0.f,0.f,0.f},{0.f,0.f,0.f,0.f},
                        {0.f,0.f,0.f,0.f},{0.f,0.f,0.f,0.f}};
#pragma unroll
        for (int ks = 0; ks < 8; ++ks) {
            float4 a0 = xv[2 * ks];
            float4 a1 = xv[2 * ks + 1];
            float f[8] = {a0.x, a0.y, a0.z, a0.w, a1.x, a1.y, a1.z, a1.w};
            bf16x8 ah, al;
#pragma unroll
            for (int i = 0; i < 8; ++i) {
                ushort hu, lu;
                split_bf16(f[i], hu, lu);
                ah[i] = (short)hu;
                al[i] = (short)lu;
            }
#pragma unroll
            for (int nt = 0; nt < 4; ++nt) {
                bf16x8 wh = whf[(ks * 4 + nt) * 64 + lane];
                bf16x8 wl = wlf[(ks * 4 + nt) * 64 + lane];
                acc[nt] = __builtin_amdgcn_mfma_f32_16x16x32_bf16(ah, wh, acc[nt], 0, 0, 0);
                acc[nt] = __builtin_amdgcn_mfma_f32_16x16x32_bf16(al, wh, acc[nt], 0, 0, 0);
                acc[nt] = __builtin_amdgcn_mfma_f32_16x16x32_bf16(ah, wl, acc[nt], 0, 0, 0);
            }
        }

        int r0 = mb * 16 + kg * 4;
        float dr[4];
#pragma unroll
        for (int j = 0; j < 4; ++j) dr[j] = dinv[r0 + j];
#pragma unroll
        for (int nt = 0; nt < 4; ++nt) {
#pragma unroll
            for (int j = 0; j < 4; ++j) {
                float v = fmaxf(acc[nt][j] + bias[nt], 0.0f) * dr[j];
                float p = __shfl_xor(v, 1, 64);  // partner column (m^1)
                if ((m & 1) == 0) {
                    uint u = pack2(bf16_rne(v), bf16_rne(p));
                    AsOut[(size_t)(r0 + j) * 32 + ((nt * 16 + m) >> 1)] = u;
                }
            }
        }

        if (!has_next) break;
#pragma unroll
        for (int u = 0; u < 16; ++u) xv[u] = xn[u];
        mb = mbn;
    }
}

// ---------------- fused FAGCN layer over pre-scaled bf16 features ----------------
// one wave per node; lanes 0-31 own feature pairs (2q,2q+1), lanes 32-63 mirror.

template <bool LAST>
__global__ void fagcn_layer(const uint* __restrict__ As, void* __restrict__ Out,
                            const float* __restrict__ dinv,
                            const int* __restrict__ rowptr,
                            const ushort* __restrict__ src,
                            const float* __restrict__ att_l, int N) {
    int t = blockIdx.x * blockDim.x + threadIdx.x;
    int i = t >> 6;
    int lane = t & 63;
    int q = lane & 31;
    if (i >= N) return;
    int start = rowptr[i];
    int end = rowptr[i + 1];
    uint su = As[(size_t)i * 32 + q];
    float self0 = __uint_as_float(su << 16);
    float self1 = __uint_as_float(su & 0xffff0000u);
    float a0 = 0.f, a1 = 0.f, b0 = 0.f, b1 = 0.f;
    int j = start;
    for (; j + 3 < end; j += 4) {
        int s0 = src[j];
        int s1 = src[j + 1];
        int s2 = src[j + 2];
        int s3 = src[j + 3];
        uint u0 = As[(size_t)s0 * 32 + q];
        uint u1 = As[(size_t)s1 * 32 + q];
        uint u2 = As[(size_t)s2 * 32 + q];
        uint u3 = As[(size_t)s3 * 32 + q];
        a0 += __uint_as_float(u0 << 16); a1 += __uint_as_float(u0 & 0xffff0000u);
        b0 += __uint_as_float(u1 << 16); b1 += __uint_as_float(u1 & 0xffff0000u);
        a0 += __uint_as_float(u2 << 16); a1 += __uint_as_float(u2 & 0xffff0000u);
        b0 += __uint_as_float(u3 << 16); b1 += __uint_as_float(u3 & 0xffff0000u);
    }
    for (; j < end; ++j) {
        int s = src[j];
        uint u = As[(size_t)s * 32 + q];
        a0 += __uint_as_float(u << 16);
        a1 += __uint_as_float(u & 0xffff0000u);
    }
    float acc0 = a0 + b0;
    float acc1 = a1 + b1;
    float d = dinv[i];
    // gate = sigmoid(dot(h_row, att)) with h = As/d
    float2 at = reinterpret_cast<const float2*>(att_l)[q];
    float prod = self0 * at.x + self1 * at.y;
#pragma unroll
    for (int off = 16; off > 0; off >>= 1)
        prod += __shfl_xor(prod, off, 64);   // fold within each 32-lane half
    float gate = 1.0f / (1.0f + expf(-prod / d));
    float factor = gate * (1.0f + EPS) - EPS;
    float h0 = d * (acc0 + self0) * factor;
    float h1 = d * (acc1 + self1) * factor;
    if (lane < 32) {
        if (LAST) {
            reinterpret_cast<float2*>(Out)[(size_t)i * 32 + q] = make_float2(h0, h1);
        } else {
            reinterpret_cast<uint*>(Out)[(size_t)i * 32 + q] =
                pack2(bf16_rne(d * h0), bf16_rne(d * h1));
        }
    }
}

// ---------------- out = h @ W2 + b2, 16 lanes per row ----------------

__global__ void gemm2(const float* __restrict__ h, const float* __restrict__ W2,
                      const float* __restrict__ b2, float* __restrict__ out, int N) {
    int t = blockIdx.x * blockDim.x + threadIdx.x;
    int r = t >> 4;
    int c = t & 15;
    if (r >= N) return;
    const float4* hr = reinterpret_cast<const float4*>(h + (size_t)r * N_HID);
    float acc = b2[c];
#pragma unroll
    for (int k4 = 0; k4 < N_HID / 4; ++k4) {
        float4 hv = hr[k4];
        int k = k4 * 4;
        acc = fmaf(hv.x, W2[(k + 0) * N_OUT + c], acc);
        acc = fmaf(hv.y, W2[(k + 1) * N_OUT + c], acc);
        acc = fmaf(hv.z, W2[(k + 2) * N_OUT + c], acc);
        acc = fmaf(hv.w, W2[(k + 3) * N_OUT + c], acc);
    }
    out[(size_t)r * N_OUT + c] = acc;
}

extern "C" void kernel_launch(void* const* d_in, const int* in_sizes, int n_in,
                              void* d_out, int out_size, void* d_ws, size_t ws_size,
                              hipStream_t stream) {
    const float* x   = (const float*)d_in[0];   // [N, 256]
    const int*   ei  = (const int*)d_in[1];     // [2, E] flat (int32 per harness)
    const float* W1  = (const float*)d_in[2];   // [256, 64]
    const float* b1  = (const float*)d_in[3];   // [64]
    const float* att = (const float*)d_in[4];   // [L, 1, 64]
    const float* W2  = (const float*)d_in[5];   // [64, 16]
    const float* b2  = (const float*)d_in[6];   // [16]
    float* out = (float*)d_out;                 // [N, 16]

    const int N = in_sizes[0] / N_FEAT_IN;      // 50000 (< 65536: ushort src ids)
    const int E = in_sizes[1] / 2;              // 800000
    const int L = in_sizes[4] / N_HID;          // 2 layers

    const int* row = ei;       // edge_index[0] (source)
    const int* col = ei + E;   // edge_index[1] (target)

    // workspace layout (256B-aligned regions)
    char* wp = (char*)d_ws;
    auto alloc = [&](size_t bytes) -> char* {
        char* p = wp;
        wp += (bytes + 255) & ~(size_t)255;
        return p;
    };
    float*  dinv    = (float*)alloc((size_t)N * 4);
    int*    cnt     = (int*)alloc((size_t)N * 4);
    int*    rowptr  = (int*)alloc((size_t)(N + 1) * 4);
    int*    pos     = (int*)alloc((size_t)N * 4);
    int*    partial = (int*)alloc(256 * 4);
    ushort* srcidx  = (ushort*)alloc((size_t)E * 2);
    uint*   AsA     = (uint*)alloc((size_t)N * 32 * 4);   // bf16-pair features
    uint*   AsB     = (uint*)alloc((size_t)N * 32 * 4);
    float*  hF      = (float*)alloc((size_t)N * N_HID * 4);  // final layer f32

    const int TB = 256;
    const int nchunks = (N + TB - 1) / TB;      // 196 <= 256
    const int rangeSz = (N + 7) / 8;            // XCD partition width
    const int PART_GRID = 1024;                 // 128 slices x 8 ranges

    // 1) degree histogram -> dinv + CSR rowptr/pos + ushort edge sources
    zero_int<<<(N + TB - 1) / TB, TB, 0, stream>>>(cnt, N);
    hist_part<<<PART_GRID, TB, 0, stream>>>(col, cnt, E, rangeSz);
    scan_chunks<<<nchunks, TB, 0, stream>>>(cnt, rowptr, partial, dinv, N);
    scan_partials<<<1, TB, 0, stream>>>(partial, nchunks);
    scan_finish<<<nchunks, TB, 0, stream>>>(rowptr, partial, pos, N, E);
    csr_fill_part<<<PART_GRID, TB, 0, stream>>>(row, col, pos, srcidx, E, rangeSz);

    // 2) As1 = dinv * relu(x @ W1 + b1) -> AsA (bf16 pairs)
    {
        const int blocks = 512;                 // 64 KB LDS -> 2 blocks/CU
        const int MB = N / 16;                  // 3125 row-tiles
        gemm1_mfma<<<blocks, TB, 0, stream>>>(x, W1, b1, dinv, AsA, MB, blocks * 4);
    }

    // 3) FAGCN layers (weight-free gather over pre-scaled features)
    {
        long long threads = (long long)N * 64;
        int grid = (int)((threads + TB - 1) / TB);
        uint* A = AsA;
        uint* B = AsB;
        for (int l = 0; l < L; ++l) {
            const float* att_l = att + (size_t)l * N_HID;
            if (l == L - 1) {
                fagcn_layer<true><<<grid, TB, 0, stream>>>(A, hF, dinv, rowptr, srcidx, att_l, N);
            } else {
                fagcn_layer<false><<<grid, TB, 0, stream>>>(A, B, dinv, rowptr, srcidx, att_l, N);
                uint* tmp = A; A = B; B = tmp;
            }
        }
    }

    // 4) out = hF @ W2 + b2
    {
        long long threads = (long long)N * N_OUT;
        gemm2<<<(int)((threads + TB - 1) / TB), TB, 0, stream>>>(hF, W2, b2, out, N);
    }
}

// Round 9
// 138.073 us; speedup vs baseline: 4.5335x; 1.4556x over previous
//
#include <hip/hip_runtime.h>
#include <math.h>

#define N_FEAT_IN 256
#define N_HID 64
#define N_OUT 16
#define EPS 0.1f

typedef short bf16x8 __attribute__((ext_vector_type(8)));
typedef float f32x4 __attribute__((ext_vector_type(4)));

__device__ inline uint pack2(ushort a, ushort b) { return (uint)a | ((uint)b << 16); }

// fp32 -> bf16 round-to-nearest-even (inputs finite; no NaN handling needed)
__device__ inline ushort bf16_rne(float x) {
    uint b = __float_as_uint(x);
    b += 0x7fff + ((b >> 16) & 1);
    return (ushort)(b >> 16);
}

// unpack the two bf16 halves of a uint
__device__ inline float blo(uint u) { return __uint_as_float(u << 16); }
__device__ inline float bhi(uint u) { return __uint_as_float(u & 0xffff0000u); }

// truncation-based fp32 -> bf16 hi/lo split: x ~= hi + lo, |err| <= 2^-18 |x|
__device__ inline void split_bf16(float x, ushort& hi, ushort& lo) {
    uint b = __float_as_uint(x);
    hi = (ushort)(b >> 16);
    float xl = x - __uint_as_float(b & 0xffff0000u);
    lo = (ushort)(__float_as_uint(xl) >> 16);
}

// ---------------- zero (runtime fillBuffer is ~40us inside a graph) ----------------

__global__ void zero_int(int* __restrict__ p, int n) {
    int i = blockIdx.x * blockDim.x + threadIdx.x;
    if (i < n) p[i] = 0;
}

// ---------------- degree histogram, fused rank capture ----------------
// One atomic pass total: the atomic's return value IS the edge's rank among its
// target's edges. rank[] write is sequential/coalesced (3.2 MB).

__global__ void hist_rank(const int* __restrict__ col, int* __restrict__ cnt,
                          int* __restrict__ rank, int E) {
    int e = blockIdx.x * blockDim.x + threadIdx.x;
    if (e < E) rank[e] = atomicAdd(&cnt[col[e]], 1);
}

// ---------------- 2-level exclusive scan (N <= 256*256), dinv fused ----------------

__global__ void scan_chunks(const int* __restrict__ cnt, int* __restrict__ rowptr,
                            int* __restrict__ partial, float* __restrict__ dinv, int N) {
    __shared__ int sm[256];
    int tid = threadIdx.x;
    int gid = blockIdx.x * 256 + tid;
    int v = (gid < N) ? cnt[gid] : 0;
    sm[tid] = v;
    __syncthreads();
#pragma unroll
    for (int off = 1; off < 256; off <<= 1) {
        int add = (tid >= off) ? sm[tid - off] : 0;
        __syncthreads();
        sm[tid] += add;
        __syncthreads();
    }
    if (gid < N) {
        rowptr[gid] = sm[tid] - v;               // exclusive within chunk
        dinv[gid] = rsqrtf(1.0f + (float)v);     // +1 for self loop
    }
    if (tid == 255) partial[blockIdx.x] = sm[255];
}

__global__ void scan_partials(int* __restrict__ partial, int nchunks) {
    __shared__ int sm[256];
    int tid = threadIdx.x;
    int v = (tid < nchunks) ? partial[tid] : 0;
    sm[tid] = v;
    __syncthreads();
#pragma unroll
    for (int off = 1; off < 256; off <<= 1) {
        int add = (tid >= off) ? sm[tid - off] : 0;
        __syncthreads();
        sm[tid] += add;
        __syncthreads();
    }
    if (tid < nchunks) partial[tid] = sm[tid] - v;
}

__global__ void scan_finish(int* __restrict__ rowptr, const int* __restrict__ partial,
                            int N, int E) {
    int gid = blockIdx.x * 256 + threadIdx.x;
    if (gid < N) rowptr[gid] += partial[blockIdx.x];
    if (gid == 0) rowptr[N] = E;
}

// ---------------- atomic-free XCD-range-partitioned CSR scatter ----------------
// srcidx[rowptr[c] + rank[e]] = row[e]; ranks are a bijection onto [0, deg(c)).
// Range partitioning (block&7 -> XCD round-robin) keeps each srcidx line in one
// XCD's L2 so it writes back once.

__global__ void csr_scatter_part(const int* __restrict__ row, const int* __restrict__ col,
                                 const int* __restrict__ rank, const int* __restrict__ rowptr,
                                 ushort* __restrict__ srcidx, int E, int rangeSz) {
    int r = blockIdx.x & 7;
    int nsl = gridDim.x >> 3;
    int s = blockIdx.x >> 3;
    int lo = r * rangeSz;
    int hi = lo + rangeSz;
    int stride = nsl * blockDim.x;
    for (int e = s * blockDim.x + threadIdx.x; e < E; e += stride) {
        int c = col[e];
        if (c >= lo && c < hi) {
            srcidx[rowptr[c] + rank[e]] = (ushort)row[e];
        }
    }
}

// ---------------- As1 = dinv * relu(x @ W1 + b1), bf16-packed, via bf16x3 MFMA --------
// Each wave: 16 rows x 64 cols, register double-buffered x tiles.
// W1 hi/lo fragments staged once per block in LDS (64 KB -> 2 blocks/CU).
// A/B K-mapping k=(lane>>4)*8+i used identically for both operands (K-perm invariant).
// C/D: col=lane&15, row=(lane>>4)*4+reg.

__global__ __launch_bounds__(256) void gemm1_mfma(const float* __restrict__ x,
                                                  const float* __restrict__ W1,
                                                  const float* __restrict__ b1,
                                                  const float* __restrict__ dinv,
                                                  uint* __restrict__ AsOut,
                                                  int MB, int totalWaves) {
    __shared__ uint4 wh_lds[2048];  // 32 KB: [ks][nt][lane] hi fragments
    __shared__ uint4 wl_lds[2048];  // 32 KB: lo fragments
    int tid = threadIdx.x;
    for (int e = tid; e < 2048; e += 256) {
        int ks = e >> 8;
        int rem = e & 255;
        int nt = rem >> 6;
        int ln = rem & 63;
        int k0 = ks * 32 + ((ln >> 4) << 3);
        int colw = nt * 16 + (ln & 15);
        ushort hi[8], lo[8];
#pragma unroll
        for (int i = 0; i < 8; ++i) {
            float v = W1[(k0 + i) * 64 + colw];
            split_bf16(v, hi[i], lo[i]);
        }
        wh_lds[e] = make_uint4(pack2(hi[0], hi[1]), pack2(hi[2], hi[3]),
                               pack2(hi[4], hi[5]), pack2(hi[6], hi[7]));
        wl_lds[e] = make_uint4(pack2(lo[0], lo[1]), pack2(lo[2], lo[3]),
                               pack2(lo[4], lo[5]), pack2(lo[6], lo[7]));
    }
    __syncthreads();

    int lane = tid & 63;
    int m = lane & 15;
    int kg = lane >> 4;
    int wid = blockIdx.x * 4 + (tid >> 6);
    const bf16x8* whf = reinterpret_cast<const bf16x8*>(wh_lds);
    const bf16x8* wlf = reinterpret_cast<const bf16x8*>(wl_lds);
    float bias[4];
#pragma unroll
    for (int nt = 0; nt < 4; ++nt) bias[nt] = b1[nt * 16 + m];

    auto load_tile = [&](float4* dst, int mbv) {
        const float4* xr = reinterpret_cast<const float4*>(x) +
                           (size_t)(mbv * 16 + m) * 64 + kg * 2;
#pragma unroll
        for (int ks = 0; ks < 8; ++ks) {
            dst[2 * ks]     = xr[ks * 8];
            dst[2 * ks + 1] = xr[ks * 8 + 1];
        }
    };

    int mb = wid;
    if (mb >= MB) return;
    float4 xv[16], xn[16];
    load_tile(xv, mb);

    while (true) {
        int mbn = mb + totalWaves;
        bool has_next = (mbn < MB);
        if (has_next) load_tile(xn, mbn);   // issue loads early; hide under MFMA

        f32x4 acc[4] = {{0.f,0.f,0.f,0.f},{0.f,0.f,0.f,0.f},
                        {0.f,0.f,0.f,0.f},{0.f,0.f,0.f,0.f}};
#pragma unroll
        for (int ks = 0; ks < 8; ++ks) {
            float4 a0 = xv[2 * ks];
            float4 a1 = xv[2 * ks + 1];
            float f[8] = {a0.x, a0.y, a0.z, a0.w, a1.x, a1.y, a1.z, a1.w};
            bf16x8 ah, al;
#pragma unroll
            for (int i = 0; i < 8; ++i) {
                ushort hu, lu;
                split_bf16(f[i], hu, lu);
                ah[i] = (short)hu;
                al[i] = (short)lu;
            }
#pragma unroll
            for (int nt = 0; nt < 4; ++nt) {
                bf16x8 wh = whf[(ks * 4 + nt) * 64 + lane];
                bf16x8 wl = wlf[(ks * 4 + nt) * 64 + lane];
                acc[nt] = __builtin_amdgcn_mfma_f32_16x16x32_bf16(ah, wh, acc[nt], 0, 0, 0);
                acc[nt] = __builtin_amdgcn_mfma_f32_16x16x32_bf16(al, wh, acc[nt], 0, 0, 0);
                acc[nt] = __builtin_amdgcn_mfma_f32_16x16x32_bf16(ah, wl, acc[nt], 0, 0, 0);
            }
        }

        int r0 = mb * 16 + kg * 4;
        float dr[4];
#pragma unroll
        for (int j = 0; j < 4; ++j) dr[j] = dinv[r0 + j];
#pragma unroll
        for (int nt = 0; nt < 4; ++nt) {
#pragma unroll
            for (int j = 0; j < 4; ++j) {
                float v = fmaxf(acc[nt][j] + bias[nt], 0.0f) * dr[j];
                float p = __shfl_xor(v, 1, 64);  // partner column (m^1)
                if ((m & 1) == 0) {
                    uint u = pack2(bf16_rne(v), bf16_rne(p));
                    AsOut[(size_t)(r0 + j) * 32 + ((nt * 16 + m) >> 1)] = u;
                }
            }
        }

        if (!has_next) break;
#pragma unroll
        for (int u = 0; u < 16; ++u) xv[u] = xn[u];
        mb = mbn;
    }
}

// ---------------- fused FAGCN layer, 4 nodes per wave ----------------
// 16 lanes per node, each lane owns 4 features (uint2 of bf16 pairs). One gather
// instruction fetches 512 B useful (4 rows) vs 128 B in the old mirrored layout.
// LAST variant fuses out = h @ W2 + b2 via LDS (deletes gemm2 + hF round-trip).

template <bool LAST>
__global__ __launch_bounds__(256) void fagcn_layer(
    const uint2* __restrict__ As2, uint2* __restrict__ Out2,
    const float* __restrict__ dinv, const int* __restrict__ rowptr,
    const ushort* __restrict__ src, const float* __restrict__ att_l,
    const float* __restrict__ W2, const float* __restrict__ b2,
    float* __restrict__ out, int N) {
    __shared__ float W2s[64 * 16];   // 4 KB
    __shared__ float hL[16 * 68];    // 16 nodes x 64 (stride 68: bank-spread, 16B-aligned rows)
    int tid = threadIdx.x;
    if (LAST) {
        for (int e = tid; e < 64 * 16; e += 256) W2s[e] = W2[e];
        __syncthreads();
    }
    int sub = tid & 15;              // feature quad index
    int lnode = tid >> 4;            // node within block (0..15)
    int i = blockIdx.x * 16 + lnode;
    if (i >= N) i = N - 1;           // duplicate last node (writes identical values)

    int start = rowptr[i];
    int end = rowptr[i + 1];
    uint2 su = As2[(size_t)i * 16 + sub];
    float self0 = blo(su.x), self1 = bhi(su.x);
    float self2 = blo(su.y), self3 = bhi(su.y);

    float aA0 = 0.f, aA1 = 0.f, aA2 = 0.f, aA3 = 0.f;
    float aB0 = 0.f, aB1 = 0.f, aB2 = 0.f, aB3 = 0.f;
    int j = start;
    for (; j + 3 < end; j += 4) {
        int s0 = src[j];
        int s1 = src[j + 1];
        int s2 = src[j + 2];
        int s3 = src[j + 3];
        uint2 u0 = As2[(size_t)s0 * 16 + sub];
        uint2 u1 = As2[(size_t)s1 * 16 + sub];
        uint2 u2 = As2[(size_t)s2 * 16 + sub];
        uint2 u3 = As2[(size_t)s3 * 16 + sub];
        aA0 += blo(u0.x); aA1 += bhi(u0.x); aA2 += blo(u0.y); aA3 += bhi(u0.y);
        aB0 += blo(u1.x); aB1 += bhi(u1.x); aB2 += blo(u1.y); aB3 += bhi(u1.y);
        aA0 += blo(u2.x); aA1 += bhi(u2.x); aA2 += blo(u2.y); aA3 += bhi(u2.y);
        aB0 += blo(u3.x); aB1 += bhi(u3.x); aB2 += blo(u3.y); aB3 += bhi(u3.y);
    }
    for (; j < end; ++j) {
        int s = src[j];
        uint2 u = As2[(size_t)s * 16 + sub];
        aA0 += blo(u.x); aA1 += bhi(u.x); aA2 += blo(u.y); aA3 += bhi(u.y);
    }
    float acc0 = aA0 + aB0, acc1 = aA1 + aB1;
    float acc2 = aA2 + aB2, acc3 = aA3 + aB3;

    float d = dinv[i];
    // gate = sigmoid(dot(h_row, att)) with h = As/d
    float4 at = reinterpret_cast<const float4*>(att_l)[sub];
    float prod = self0 * at.x + self1 * at.y + self2 * at.z + self3 * at.w;
#pragma unroll
    for (int off = 8; off > 0; off >>= 1)
        prod += __shfl_xor(prod, off, 64);   // fold within 16-lane group
    float gate = 1.0f / (1.0f + expf(-prod / d));
    float factor = gate * (1.0f + EPS) - EPS;
    float h0 = d * (acc0 + self0) * factor;
    float h1 = d * (acc1 + self1) * factor;
    float h2 = d * (acc2 + self2) * factor;
    float h3 = d * (acc3 + self3) * factor;

    if (!LAST) {
        Out2[(size_t)i * 16 + sub] =
            make_uint2(pack2(bf16_rne(d * h0), bf16_rne(d * h1)),
                       pack2(bf16_rne(d * h2), bf16_rne(d * h3)));
    } else {
        // fused gemm2: h -> LDS, then 16 lanes x 16 output cols per node
        float* hrow = &hL[lnode * 68];
        hrow[4 * sub + 0] = h0;
        hrow[4 * sub + 1] = h1;
        hrow[4 * sub + 2] = h2;
        hrow[4 * sub + 3] = h3;
        __syncthreads();
        const float4* h4 = reinterpret_cast<const float4*>(hrow);
        float acc = b2[sub];
#pragma unroll
        for (int k4 = 0; k4 < 16; ++k4) {
            float4 hv = h4[k4];
            int k = 4 * k4;
            acc = fmaf(hv.x, W2s[(k + 0) * 16 + sub], acc);
            acc = fmaf(hv.y, W2s[(k + 1) * 16 + sub], acc);
            acc = fmaf(hv.z, W2s[(k + 2) * 16 + sub], acc);
            acc = fmaf(hv.w, W2s[(k + 3) * 16 + sub], acc);
        }
        out[(size_t)i * 16 + sub] = acc;
    }
}

extern "C" void kernel_launch(void* const* d_in, const int* in_sizes, int n_in,
                              void* d_out, int out_size, void* d_ws, size_t ws_size,
                              hipStream_t stream) {
    const float* x   = (const float*)d_in[0];   // [N, 256]
    const int*   ei  = (const int*)d_in[1];     // [2, E] flat (int32 per harness)
    const float* W1  = (const float*)d_in[2];   // [256, 64]
    const float* b1  = (const float*)d_in[3];   // [64]
    const float* att = (const float*)d_in[4];   // [L, 1, 64]
    const float* W2  = (const float*)d_in[5];   // [64, 16]
    const float* b2  = (const float*)d_in[6];   // [16]
    float* out = (float*)d_out;                 // [N, 16]

    const int N = in_sizes[0] / N_FEAT_IN;      // 50000 (< 65536: ushort src ids)
    const int E = in_sizes[1] / 2;              // 800000
    const int L = in_sizes[4] / N_HID;          // 2 layers

    const int* row = ei;       // edge_index[0] (source)
    const int* col = ei + E;   // edge_index[1] (target)

    // workspace layout (256B-aligned regions)
    char* wp = (char*)d_ws;
    auto alloc = [&](size_t bytes) -> char* {
        char* p = wp;
        wp += (bytes + 255) & ~(size_t)255;
        return p;
    };
    float*  dinv    = (float*)alloc((size_t)N * 4);
    int*    cnt     = (int*)alloc((size_t)N * 4);
    int*    rowptr  = (int*)alloc((size_t)(N + 1) * 4);
    int*    rank    = (int*)alloc((size_t)E * 4);
    int*    partial = (int*)alloc(256 * 4);
    ushort* srcidx  = (ushort*)alloc((size_t)E * 2);
    uint*   AsA     = (uint*)alloc((size_t)N * 32 * 4);   // bf16-pair features
    uint*   AsB     = (uint*)alloc((size_t)N * 32 * 4);

    const int TB = 256;
    const int nchunks = (N + TB - 1) / TB;      // 196 <= 256
    const int rangeSz = (N + 7) / 8;            // XCD partition width
    const int PART_GRID = 1024;                 // 128 slices x 8 ranges

    // 1) degree+rank in ONE atomic pass -> dinv, rowptr; atomic-free CSR scatter
    zero_int<<<(N + TB - 1) / TB, TB, 0, stream>>>(cnt, N);
    hist_rank<<<(E + TB - 1) / TB, TB, 0, stream>>>(col, cnt, rank, E);
    scan_chunks<<<nchunks, TB, 0, stream>>>(cnt, rowptr, partial, dinv, N);
    scan_partials<<<1, TB, 0, stream>>>(partial, nchunks);
    scan_finish<<<nchunks, TB, 0, stream>>>(rowptr, partial, N, E);
    csr_scatter_part<<<PART_GRID, TB, 0, stream>>>(row, col, rank, rowptr, srcidx, E, rangeSz);

    // 2) As1 = dinv * relu(x @ W1 + b1) -> AsA (bf16 pairs)
    {
        const int blocks = 512;                 // 64 KB LDS -> 2 blocks/CU
        const int MB = N / 16;                  // 3125 row-tiles
        gemm1_mfma<<<blocks, TB, 0, stream>>>(x, W1, b1, dinv, AsA, MB, blocks * 4);
    }

    // 3) FAGCN layers; LAST fuses the final h @ W2 + b2
    {
        int grid = (N + 15) / 16;               // 16 nodes per 256-thread block
        uint2* A = (uint2*)AsA;
        uint2* B = (uint2*)AsB;
        for (int l = 0; l < L; ++l) {
            const float* att_l = att + (size_t)l * N_HID;
            if (l == L - 1) {
                fagcn_layer<true><<<grid, TB, 0, stream>>>(
                    A, B, dinv, rowptr, srcidx, att_l, W2, b2, out, N);
            } else {
                fagcn_layer<false><<<grid, TB, 0, stream>>>(
                    A, B, dinv, rowptr, srcidx, att_l, W2, b2, out, N);
                uint2* tmp = A; A = B; B = tmp;
            }
        }
    }
}